// Round 12
// baseline (120.897 us; speedup 1.0000x reference)
//
#include <hip/hip_runtime.h>
#include <stdint.h>

#define NT 5
#define NC 32
#define NH 4
#define HW 4096             // 64*64
#define NPIX 40960          // (b*t)*HW
#define QS 0.51006972789f   // (1/sqrt(8)) * log2(e): fold scale + ln->log2 into q
#define EBIAS 12.0f         // softmax shift: p = 2^(e-EBIAS); cancels in acc/l
#define NINF (-__builtin_inff())

typedef _Float16 half_t;
typedef half_t h2 __attribute__((ext_vector_type(2)));

static __device__ __forceinline__ h2 as_h2(uint32_t u) {
  union { uint32_t u; h2 h; } c; c.u = u; return c.h;
}
static __device__ __forceinline__ uint32_t pack_h2(float a, float b) {
  union { h2 h; uint32_t u; } c;
  c.h.x = (half_t)a; c.h.y = (half_t)b;
  return c.u;
}

#if __has_builtin(__builtin_amdgcn_exp2f)
#define EXP2(x) __builtin_amdgcn_exp2f(x)
#else
#define EXP2(x) exp2f(x)
#endif

// dot8 with runtime init accumulator (carries -EBIAS and the 0/-inf masks free)
static __device__ __forceinline__ float dot8i(const uint4& a, const uint4& b, float c) {
#if __has_builtin(__builtin_amdgcn_fdot2)
  c = __builtin_amdgcn_fdot2(as_h2(a.x), as_h2(b.x), c, false);
  c = __builtin_amdgcn_fdot2(as_h2(a.y), as_h2(b.y), c, false);
  c = __builtin_amdgcn_fdot2(as_h2(a.z), as_h2(b.z), c, false);
  c = __builtin_amdgcn_fdot2(as_h2(a.w), as_h2(b.w), c, false);
  return c;
#else
  const h2 a0 = as_h2(a.x), a1 = as_h2(a.y), a2 = as_h2(a.z), a3 = as_h2(a.w);
  const h2 b0 = as_h2(b.x), b1 = as_h2(b.y), b2 = as_h2(b.z), b3 = as_h2(b.w);
  c = fmaf((float)a0.x, (float)b0.x, c);
  c = fmaf((float)a0.y, (float)b0.y, c);
  c = fmaf((float)a1.x, (float)b1.x, c);
  c = fmaf((float)a1.y, (float)b1.y, c);
  c = fmaf((float)a2.x, (float)b2.x, c);
  c = fmaf((float)a2.y, (float)b2.y, c);
  c = fmaf((float)a3.x, (float)b3.x, c);
  c = fmaf((float)a3.y, (float)b3.y, c);
  return c;
#endif
}

// ---------------- Kernel A: QKV projection (R13 proven: ~11 us) -------------
// Split per (head x output-quad): dim3(160,8) -> 1280 blocks, 20 waves/CU.
__global__ __launch_bounds__(256) void qkv_kernel(
    const float* __restrict__ x,
    const float* __restrict__ Wq, const float* __restrict__ Wk,
    const float* __restrict__ Wv,
    uint2* __restrict__ qf, uint2* __restrict__ kf, uint2* __restrict__ vf)
{
  const int p   = blockIdx.x * 256 + threadIdx.x;   // 0..40959
  const int by  = blockIdx.y;                       // 0..7
  const int h   = by >> 1;
  const int jg  = by & 1;
  const int bt  = p >> 12;
  const int pix = p & 4095;

  const float* xp = x + (size_t)bt * (NC * HW) + pix;
  float xc[NC];
  #pragma unroll
  for (int c = 0; c < NC; ++c) xc[c] = xp[(size_t)c * HW];

  float qv[4], kv4[4], vv4[4];
  #pragma unroll
  for (int j = 0; j < 4; ++j) {
    const int o = h * 8 + jg * 4 + j;
    float aq = 0.f, ak = 0.f, av = 0.f;
    #pragma unroll
    for (int c = 0; c < NC; ++c) {
      const float xv = xc[c];
      aq = fmaf(xv, Wq[o * NC + c], aq);
      ak = fmaf(xv, Wk[o * NC + c], ak);
      av = fmaf(xv, Wv[o * NC + c], av);
    }
    qv[j] = aq * QS; kv4[j] = ak; vv4[j] = av;
  }
  const size_t base = (((size_t)bt * NH + h) * HW + pix) * 2 + jg;
  uint2 qq, kk, vv;
  qq.x = pack_h2(qv[0], qv[1]);  qq.y = pack_h2(qv[2], qv[3]);
  kk.x = pack_h2(kv4[0], kv4[1]); kk.y = pack_h2(kv4[2], kv4[3]);
  vv.x = pack_h2(vv4[0], vv4[1]); vv.y = pack_h2(vv4[2], vv4[3]);
  qf[base] = qq;
  kf[base] = kk;
  vf[base] = vv;
}

// ---------------- Kernel B: X-PAIRED neighborhood attention -----------------
// R25: each thread owns 4 queries = (y-pair) x (x-pair of ADJACENT same-
// parity columns). X-adjacent queries share 2R of 2R+1 K columns: per key
// row the thread reads LS+1 K + LS+1 V cols serving 4 queries — per-query
// LDS reads drop 1.75-1.8x with ZERO mask waste (query x0 uses kbuf[i],
// x1 uses kbuf[i+1]). 128-thr blocks, grid stays 1600, LDS stays 32 KB.
template <int R, int D>
static __device__ __forceinline__ void attn_body(
    int b, int t, int h, int s, int yb,
    const uint4* __restrict__ qf, const uint4* __restrict__ kf,
    const uint4* __restrict__ vf,
    uint4* __restrict__ pa, float* __restrict__ pl,
    uint4* __restrict__ k_lds, uint4* __restrict__ v_lds)
{
  constexpr int LS    = 2 * R + 1;
  constexpr int NROWS = 8 + 2 * R;        // staged key rows (step D): 14 or 16
  constexpr int CMAX  = (D == 1) ? 64 : 32;   // valid compressed col range
  const int tid  = threadIdx.x;           // 0..127
  const int w    = tid >> 6;              // wave 0..1
  const int lane = tid & 63;

  // first query row of this block (D2: yb&1 = row parity, 8 same-parity rows)
  const int y0 = (D == 1) ? (yb * 8) : ((yb & 1) + 2 * ((yb >> 1) * 8));

  // ---- stage NROWS full-width K,V rows into LDS (coalesced) ----
  const uint4* kg = kf + (size_t)((b * NT + s) * NH + h) * HW;
  const uint4* vg = vf + (size_t)((b * NT + s) * NH + h) * HW;
  for (int idx = tid; idx < NROWS * 64; idx += 128) {
    const int r  = idx >> 6, xs = idx & 63;
    int ys = y0 + (r - R) * D;
    ys = ys < 0 ? 0 : (ys > 63 ? 63 : ys);          // clamp; masked at compute
    const int pos = (D == 1) ? xs : ((xs & 1) * 32 + (xs >> 1));
    k_lds[r * 64 + pos] = kg[ys * 64 + xs];
    v_lds[r * 64 + pos] = vg[ys * 64 + xs];
  }
  __syncthreads();

  // thread -> (row-pair rp, parity xp, col-pair j)
  // D1: rp = 2w + (lane>>5), j = lane&31, cc0 = 2j       (xp unused)
  // D2: rp = 2w + ((lane>>4)&1), xp = lane>>5, j = lane&15, cc0 = 2j
  const int rp  = (D == 1) ? (2 * w + (lane >> 5)) : (2 * w + ((lane >> 4) & 1));
  const int xp  = (D == 1) ? 0 : (lane >> 5);
  const int j   = (D == 1) ? (lane & 31) : (lane & 15);
  const int cc0 = 2 * j;                             // compressed col of query x0

  // physical x of the two queries
  const int x0 = (D == 1) ? cc0 : (2 * cc0 + xp);
  const int x1 = (D == 1) ? (cc0 + 1) : (2 * (cc0 + 1) + xp);

  const int yA = y0 + 2 * rp * D;
  const int yB = yA + D;
  const int pixA0 = yA * 64 + x0, pixA1 = yA * 64 + x1;
  const int pixB0 = yB * 64 + x0, pixB1 = yB * 64 + x1;

  const uint4* qp = qf + (size_t)((b * NT + t) * NH + h) * HW;
  const uint4 qA0 = qp[pixA0], qA1 = qp[pixA1];
  const uint4 qB0 = qp[pixB0], qB1 = qp[pixB1];

  // ---- col-invariant hoisting: LDS position + col mask per window slot ----
  // slot i covers compressed col cc0 - R + i, i in [0, LS] (LS+1 slots)
  int   posArr[LS + 1];
  float eoArr[LS + 1];
  #pragma unroll
  for (int i = 0; i <= LS; ++i) {
    const int  cx  = cc0 - R + i;
    const bool okx = (unsigned)cx < (unsigned)CMAX;
    const int  cc  = okx ? cx : 0;
    posArr[i] = (D == 1) ? cc : (xp * 32 + cc);
    eoArr[i]  = okx ? 0.f : NINF;
  }

  float lA0 = 0.f, lA1 = 0.f, lB0 = 0.f, lB1 = 0.f;
  h2 aA0[4], aA1[4], aB0[4], aB1[4];
  const h2 z2 = { (half_t)0.f, (half_t)0.f };
  #pragma unroll
  for (int i = 0; i < 4; ++i) { aA0[i] = z2; aA1[i] = z2; aB0[i] = z2; aB1[i] = z2; }

  #pragma unroll 1
  for (int u = 0; u <= LS; ++u) {                    // key-row sweep, pair-shared
    const int ykey = y0 + (2 * rp + u - R) * D;      // key row y (same for A,B)
    const bool oky = (unsigned)ykey < 64u;
    const bool okA = (u < LS) && oky;
    const bool okB = (u > 0)  && oky;
    if (!(okA || okB)) continue;                     // wave-uniform skip
    const float biA = okA ? -EBIAS : NINF;           // row mask folded into dot
    const float biB = okB ? -EBIAS : NINF;
    const uint4* kr = k_lds + (2 * rp + u) * 64;
    const uint4* vr = v_lds + (2 * rp + u) * 64;

    // ---- load the whole window once: LS+1 K cols + LS+1 V cols ----
    uint4 kbuf[LS + 1], vbuf[LS + 1];
    #pragma unroll
    for (int i = 0; i <= LS; ++i) {
      kbuf[i] = kr[posArr[i]];
      vbuf[i] = vr[posArr[i]];
    }

    #pragma unroll
    for (int i = 0; i < LS; ++i) {                   // dx slot for query x0
      const float ciA0 = biA + eoArr[i];
      const float ciA1 = biA + eoArr[i + 1];
      const float ciB0 = biB + eoArr[i];
      const float ciB1 = biB + eoArr[i + 1];
      const float pA0 = EXP2(dot8i(qA0, kbuf[i],     ciA0));
      const float pA1 = EXP2(dot8i(qA1, kbuf[i + 1], ciA1));
      const float pB0 = EXP2(dot8i(qB0, kbuf[i],     ciB0));
      const float pB1 = EXP2(dot8i(qB1, kbuf[i + 1], ciB1));
      lA0 += pA0; lA1 += pA1; lB0 += pB0; lB1 += pB1;
      const half_t hA0 = (half_t)pA0, hA1 = (half_t)pA1;
      const half_t hB0 = (half_t)pB0, hB1 = (half_t)pB1;
      const h2 qA0v = { hA0, hA0 }, qA1v = { hA1, hA1 };
      const h2 qB0v = { hB0, hB0 }, qB1v = { hB1, hB1 };
      const uint4 v0 = vbuf[i], v1 = vbuf[i + 1];
      const h2 w00 = as_h2(v0.x), w01 = as_h2(v0.y), w02 = as_h2(v0.z), w03 = as_h2(v0.w);
      const h2 w10 = as_h2(v1.x), w11 = as_h2(v1.y), w12 = as_h2(v1.z), w13 = as_h2(v1.w);
      aA0[0] += qA0v * w00; aA0[1] += qA0v * w01; aA0[2] += qA0v * w02; aA0[3] += qA0v * w03;
      aA1[0] += qA1v * w10; aA1[1] += qA1v * w11; aA1[2] += qA1v * w12; aA1[3] += qA1v * w13;
      aB0[0] += qB0v * w00; aB0[1] += qB0v * w01; aB0[2] += qB0v * w02; aB0[3] += qB0v * w03;
      aB1[0] += qB1v * w10; aB1[1] += qB1v * w11; aB1[2] += qB1v * w12; aB1[3] += qB1v * w13;
    }
  }

  // ---- store frame-partials: pa/pl [s][h][btpix], each written once ----
  const size_t plane = (size_t)(s * NH + h) * NPIX + (size_t)(b * NT + t) * HW;
  union { h2 hh[4]; uint4 u; } c0, c1, c2, c3;
  #pragma unroll
  for (int i = 0; i < 4; ++i) { c0.hh[i] = aA0[i]; c1.hh[i] = aA1[i];
                                c2.hh[i] = aB0[i]; c3.hh[i] = aB1[i]; }
  pa[plane + pixA0] = c0.u;
  pa[plane + pixA1] = c1.u;
  pa[plane + pixB0] = c2.u;
  pa[plane + pixB1] = c3.u;
  pl[plane + pixA0] = lA0;
  pl[plane + pixA1] = lA1;
  pl[plane + pixB0] = lB0;
  pl[plane + pixB1] = lB1;
}

__global__ __launch_bounds__(128) void attn_kernel(
    const uint4* __restrict__ qf, const uint4* __restrict__ kf,
    const uint4* __restrict__ vf, uint4* __restrict__ pa, float* __restrict__ pl)
{
  __shared__ uint4 k_lds[16 * 64];   // 16 KB
  __shared__ uint4 v_lds[16 * 64];   // 16 KB
  const int bid = blockIdx.x;        // 1600 = 10(bt) * 5(s) * 8(yb) * 4(h)
  // Longest-job-first: bids 0..799 -> R4 heads {2,3}; 800..1599 -> R3 {0,1}.
  int h, rest;
  if (bid < 800) { h = 2 + (bid & 1); rest = bid >> 1; }
  else           { h = ((bid - 800) & 1); rest = (bid - 800) >> 1; }
  const int yb = rest & 7; rest >>= 3;
  const int s  = rest % 5;
  const int bt = rest / 5;
  const int t = bt % NT, b = bt / NT;
  if      (h == 0) attn_body<3, 1>(b, t, 0, s, yb, qf, kf, vf, pa, pl, k_lds, v_lds);
  else if (h == 1) attn_body<3, 2>(b, t, 1, s, yb, qf, kf, vf, pa, pl, k_lds, v_lds);
  else if (h == 2) attn_body<4, 1>(b, t, 2, s, yb, qf, kf, vf, pa, pl, k_lds, v_lds);
  else             attn_body<4, 2>(b, t, 3, s, yb, qf, kf, vf, pa, pl, k_lds, v_lds);
}

// ---------------- Kernel C1: plane reduce + normalize -> of (fp16) ----------
// R24 proven: reads the 20 planes ONCE (20 MB), normalizes, writes 2.6 MB.
// dim3(160,4) -> 640 blocks, 10 waves/CU.
__global__ __launch_bounds__(256) void reduce_kernel(
    const uint4* __restrict__ pa, const float* __restrict__ pl,
    uint4* __restrict__ of)
{
  const int p = blockIdx.x * 256 + threadIdx.x;     // btpix 0..40959
  const int h = blockIdx.y;                         // head 0..3

  float a[8], l = 0.f;
  #pragma unroll
  for (int i = 0; i < 8; ++i) a[i] = 0.f;
  #pragma unroll
  for (int s = 0; s < NT; ++s) {
    const size_t plane = (size_t)(s * NH + h) * NPIX + p;
    const uint4 v = pa[plane];
    l += pl[plane];
    const h2 v0 = as_h2(v.x), v1 = as_h2(v.y), v2 = as_h2(v.z), v3 = as_h2(v.w);
    a[0] += (float)v0.x; a[1] += (float)v0.y;
    a[2] += (float)v1.x; a[3] += (float)v1.y;
    a[4] += (float)v2.x; a[5] += (float)v2.y;
    a[6] += (float)v3.x; a[7] += (float)v3.y;
  }
  const float inv = 1.0f / l;
  uint4 r;
  r.x = pack_h2(a[0] * inv, a[1] * inv);
  r.y = pack_h2(a[2] * inv, a[3] * inv);
  r.z = pack_h2(a[4] * inv, a[5] * inv);
  r.w = pack_h2(a[6] * inv, a[7] * inv);
  of[(size_t)h * NPIX + p] = r;
}

// ---------------- Kernel C2: Wo projection + residual (R24 proven) ----------
// of holds final normalized per-head fp16x8 (2.6 MB, L2-resident).
// dim3(160,8) -> 1280 blocks, 20 waves/CU.
__global__ __launch_bounds__(256) void proj_kernel(
    const uint4* __restrict__ of, const float* __restrict__ x,
    const float* __restrict__ Wo, float* __restrict__ out)
{
  const int p   = blockIdx.x * 256 + threadIdx.x;   // btpix 0..40959
  const int og  = blockIdx.y;                       // 4 out-channels per og
  const int bt  = p >> 12;
  const int pix = p & 4095;

  float oc[32];
  #pragma unroll
  for (int h = 0; h < NH; ++h) {
    const uint4 v = of[(size_t)h * NPIX + p];
    const h2 v0 = as_h2(v.x), v1 = as_h2(v.y), v2 = as_h2(v.z), v3 = as_h2(v.w);
    oc[h * 8 + 0] = (float)v0.x; oc[h * 8 + 1] = (float)v0.y;
    oc[h * 8 + 2] = (float)v1.x; oc[h * 8 + 3] = (float)v1.y;
    oc[h * 8 + 4] = (float)v2.x; oc[h * 8 + 5] = (float)v2.y;
    oc[h * 8 + 6] = (float)v3.x; oc[h * 8 + 7] = (float)v3.y;
  }

  const float* xpt = x + (size_t)bt * (NC * HW) + pix;
  float* yp = out + (size_t)bt * (NC * HW) + pix;
  #pragma unroll
  for (int oo = 0; oo < 4; ++oo) {
    const int o = og * 4 + oo;
    float acc = xpt[(size_t)o * HW];                // residual
    #pragma unroll
    for (int c = 0; c < NC; ++c)
      acc = fmaf(oc[c], Wo[o * NC + c], acc);
    yp[(size_t)o * HW] = acc;
  }
}

extern "C" void kernel_launch(void* const* d_in, const int* in_sizes, int n_in,
                              void* d_out, int out_size, void* d_ws, size_t ws_size,
                              hipStream_t stream)
{
  const float* x  = (const float*)d_in[0];
  const float* Wq = (const float*)d_in[1];
  const float* Wk = (const float*)d_in[2];
  const float* Wv = (const float*)d_in[3];
  const float* Wo = (const float*)d_in[4];

  char* ws = (char*)d_ws;
  uint2* qf = (uint2*)ws;                             //  2,621,440 B
  uint2* kf = (uint2*)(ws + 2621440);                 //  2,621,440 B
  uint2* vf = (uint2*)(ws + 2 * 2621440);             //  2,621,440 B
  uint4* pa = (uint4*)(ws + 3 * 2621440);             // 13,107,200 B (fp16x8 partials)
  float* pl = (float*)(ws + 3 * 2621440 + 13107200);  //  3,276,800 B (fp32 l)
  uint4* of = (uint4*)(ws + 3 * 2621440 + 13107200 + 3276800); // 2,621,440 B

  qkv_kernel<<<dim3(160, 8), 256, 0, stream>>>(x, Wq, Wk, Wv, qf, kf, vf);
  attn_kernel<<<1600, 128, 0, stream>>>((const uint4*)qf, (const uint4*)kf,
                                        (const uint4*)vf, pa, pl);
  reduce_kernel<<<dim3(160, 4), 256, 0, stream>>>((const uint4*)pa, pl, of);
  proj_kernel<<<dim3(160, 8), 256, 0, stream>>>((const uint4*)of, x, Wo,
                                                (float*)d_out);
}

// Round 13
// 116.759 us; speedup vs baseline: 1.0354x; 1.0354x over previous
//
#include <hip/hip_runtime.h>
#include <stdint.h>

#define NT 5
#define NC 32
#define NH 4
#define HW 4096             // 64*64
#define NPIX 40960          // (b*t)*HW
#define QS 0.51006972789f   // (1/sqrt(8)) * log2(e): fold scale + ln->log2 into q
#define EBIAS 12.0f         // softmax shift: p = 2^(e-EBIAS); cancels in acc/l
#define NINF (-__builtin_inff())
#define LSTRIDE 65          // padded LDS row stride (uint4): rows 4 banks apart

typedef _Float16 half_t;
typedef half_t h2 __attribute__((ext_vector_type(2)));

static __device__ __forceinline__ h2 as_h2(uint32_t u) {
  union { uint32_t u; h2 h; } c; c.u = u; return c.h;
}
static __device__ __forceinline__ uint32_t pack_h2(float a, float b) {
  union { h2 h; uint32_t u; } c;
  c.h.x = (half_t)a; c.h.y = (half_t)b;
  return c.u;
}

#if __has_builtin(__builtin_amdgcn_exp2f)
#define EXP2(x) __builtin_amdgcn_exp2f(x)
#else
#define EXP2(x) exp2f(x)
#endif

// dot8 with runtime init accumulator (carries -EBIAS and the 0/-inf masks free)
static __device__ __forceinline__ float dot8i(const uint4& a, const uint4& b, float c) {
#if __has_builtin(__builtin_amdgcn_fdot2)
  c = __builtin_amdgcn_fdot2(as_h2(a.x), as_h2(b.x), c, false);
  c = __builtin_amdgcn_fdot2(as_h2(a.y), as_h2(b.y), c, false);
  c = __builtin_amdgcn_fdot2(as_h2(a.z), as_h2(b.z), c, false);
  c = __builtin_amdgcn_fdot2(as_h2(a.w), as_h2(b.w), c, false);
  return c;
#else
  const h2 a0 = as_h2(a.x), a1 = as_h2(a.y), a2 = as_h2(a.z), a3 = as_h2(a.w);
  const h2 b0 = as_h2(b.x), b1 = as_h2(b.y), b2 = as_h2(b.z), b3 = as_h2(b.w);
  c = fmaf((float)a0.x, (float)b0.x, c);
  c = fmaf((float)a0.y, (float)b0.y, c);
  c = fmaf((float)a1.x, (float)b1.x, c);
  c = fmaf((float)a1.y, (float)b1.y, c);
  c = fmaf((float)a2.x, (float)b2.x, c);
  c = fmaf((float)a2.y, (float)b2.y, c);
  c = fmaf((float)a3.x, (float)b3.x, c);
  c = fmaf((float)a3.y, (float)b3.y, c);
  return c;
#endif
}

// ---------------- Kernel A: QKV projection (R13 proven: ~11 us) -------------
// Split per (head x output-quad): dim3(160,8) -> 1280 blocks, 20 waves/CU.
__global__ __launch_bounds__(256) void qkv_kernel(
    const float* __restrict__ x,
    const float* __restrict__ Wq, const float* __restrict__ Wk,
    const float* __restrict__ Wv,
    uint2* __restrict__ qf, uint2* __restrict__ kf, uint2* __restrict__ vf)
{
  const int p   = blockIdx.x * 256 + threadIdx.x;   // 0..40959
  const int by  = blockIdx.y;                       // 0..7
  const int h   = by >> 1;
  const int jg  = by & 1;
  const int bt  = p >> 12;
  const int pix = p & 4095;

  const float* xp = x + (size_t)bt * (NC * HW) + pix;
  float xc[NC];
  #pragma unroll
  for (int c = 0; c < NC; ++c) xc[c] = xp[(size_t)c * HW];

  float qv[4], kv4[4], vv4[4];
  #pragma unroll
  for (int j = 0; j < 4; ++j) {
    const int o = h * 8 + jg * 4 + j;
    float aq = 0.f, ak = 0.f, av = 0.f;
    #pragma unroll
    for (int c = 0; c < NC; ++c) {
      const float xv = xc[c];
      aq = fmaf(xv, Wq[o * NC + c], aq);
      ak = fmaf(xv, Wk[o * NC + c], ak);
      av = fmaf(xv, Wv[o * NC + c], av);
    }
    qv[j] = aq * QS; kv4[j] = ak; vv4[j] = av;
  }
  const size_t base = (((size_t)bt * NH + h) * HW + pix) * 2 + jg;
  uint2 qq, kk, vv;
  qq.x = pack_h2(qv[0], qv[1]);  qq.y = pack_h2(qv[2], qv[3]);
  kk.x = pack_h2(kv4[0], kv4[1]); kk.y = pack_h2(kv4[2], kv4[3]);
  vv.x = pack_h2(vv4[0], vv4[1]); vv.y = pack_h2(vv4[2], vv4[3]);
  qf[base] = qq;
  kf[base] = kk;
  vf[base] = vv;
}

// ---------------- Kernel B: X-PAIRED attention, conflict-free LDS -----------
// R26 = R25 x-pair body + PARITY-SPLIT LDS layout + padded row stride.
// R25's 15x bank-conflict blowup came from stride-2 window reads
// (kr[2j-R+i]: bank 8j%32). Fix: store column c at slot (c>>1)+HALF*(c&1)
// so every window-slot read is stride-1 across lanes; row stride 65 uint4
// de-aliases the per-lane-group row split (rp varies within wave).
template <int R, int D>
static __device__ __forceinline__ void attn_body(
    int b, int t, int h, int s, int yb,
    const uint4* __restrict__ qf, const uint4* __restrict__ kf,
    const uint4* __restrict__ vf,
    uint4* __restrict__ pa, float* __restrict__ pl,
    uint4* __restrict__ k_lds, uint4* __restrict__ v_lds)
{
  constexpr int LS    = 2 * R + 1;
  constexpr int NROWS = 8 + 2 * R;        // staged key rows (step D): 14 or 16
  constexpr int CMAX  = (D == 1) ? 64 : 32;   // valid compressed col range
  constexpr int HALF  = (D == 1) ? 32 : 16;   // parity-split offset
  const int tid  = threadIdx.x;           // 0..127
  const int w    = tid >> 6;              // wave 0..1
  const int lane = tid & 63;

  // first query row of this block (D2: yb&1 = row parity, 8 same-parity rows)
  const int y0 = (D == 1) ? (yb * 8) : ((yb & 1) + 2 * ((yb >> 1) * 8));

  // ---- stage NROWS full-width K,V rows into LDS (parity-split layout) ----
  const uint4* kg = kf + (size_t)((b * NT + s) * NH + h) * HW;
  const uint4* vg = vf + (size_t)((b * NT + s) * NH + h) * HW;
  for (int idx = tid; idx < NROWS * 64; idx += 128) {
    const int r  = idx >> 6, xs = idx & 63;
    int ys = y0 + (r - R) * D;
    ys = ys < 0 ? 0 : (ys > 63 ? 63 : ys);          // clamp; masked at compute
    // compressed col + parity-split within (D2: within parity half)
    int pos;
    if (D == 1) {
      pos = (xs >> 1) + 32 * (xs & 1);
    } else {
      const int xpp = xs & 1, cc = xs >> 1;
      pos = xpp * 32 + (cc >> 1) + 16 * (cc & 1);
    }
    k_lds[r * LSTRIDE + pos] = kg[ys * 64 + xs];
    v_lds[r * LSTRIDE + pos] = vg[ys * 64 + xs];
  }
  __syncthreads();

  // thread -> (row-pair rp, parity xp, col-pair j)
  const int rp  = (D == 1) ? (2 * w + (lane >> 5)) : (2 * w + ((lane >> 4) & 1));
  const int xp  = (D == 1) ? 0 : (lane >> 5);
  const int j   = (D == 1) ? (lane & 31) : (lane & 15);
  const int cc0 = 2 * j;                             // compressed col of query x0

  // physical x of the two queries
  const int x0 = (D == 1) ? cc0 : (2 * cc0 + xp);
  const int x1 = (D == 1) ? (cc0 + 1) : (2 * (cc0 + 1) + xp);

  const int yA = y0 + 2 * rp * D;
  const int yB = yA + D;
  const int pixA0 = yA * 64 + x0, pixA1 = yA * 64 + x1;
  const int pixB0 = yB * 64 + x0, pixB1 = yB * 64 + x1;

  const uint4* qp = qf + (size_t)((b * NT + t) * NH + h) * HW;
  const uint4 qA0 = qp[pixA0], qA1 = qp[pixA1];
  const uint4 qB0 = qp[pixB0], qB1 = qp[pixB1];

  // ---- col-invariant hoisting: parity-split LDS slot + col mask per slot --
  // slot i covers compressed col cc0 - R + i, i in [0, LS] (LS+1 slots)
  int   posArr[LS + 1];
  float eoArr[LS + 1];
  #pragma unroll
  for (int i = 0; i <= LS; ++i) {
    const int  cx  = cc0 - R + i;
    const bool okx = (unsigned)cx < (unsigned)CMAX;
    const int  cc  = okx ? cx : 0;
    const int  sp  = (cc >> 1) + HALF * (cc & 1);    // parity-split slot
    posArr[i] = (D == 1) ? sp : (xp * 32 + sp);
    eoArr[i]  = okx ? 0.f : NINF;
  }

  float lA0 = 0.f, lA1 = 0.f, lB0 = 0.f, lB1 = 0.f;
  h2 aA0[4], aA1[4], aB0[4], aB1[4];
  const h2 z2 = { (half_t)0.f, (half_t)0.f };
  #pragma unroll
  for (int i = 0; i < 4; ++i) { aA0[i] = z2; aA1[i] = z2; aB0[i] = z2; aB1[i] = z2; }

  #pragma unroll 1
  for (int u = 0; u <= LS; ++u) {                    // key-row sweep, pair-shared
    const int ykey = y0 + (2 * rp + u - R) * D;      // key row y (same for A,B)
    const bool oky = (unsigned)ykey < 64u;
    const bool okA = (u < LS) && oky;
    const bool okB = (u > 0)  && oky;
    if (!(okA || okB)) continue;                     // wave-uniform skip
    const float biA = okA ? -EBIAS : NINF;           // row mask folded into dot
    const float biB = okB ? -EBIAS : NINF;
    const uint4* kr = k_lds + (2 * rp + u) * LSTRIDE;
    const uint4* vr = v_lds + (2 * rp + u) * LSTRIDE;

    // ---- load the whole window once: LS+1 K cols + LS+1 V cols ----
    uint4 kbuf[LS + 1], vbuf[LS + 1];
    #pragma unroll
    for (int i = 0; i <= LS; ++i) {
      kbuf[i] = kr[posArr[i]];
      vbuf[i] = vr[posArr[i]];
    }

    #pragma unroll
    for (int i = 0; i < LS; ++i) {                   // dx slot for query x0
      const float ciA0 = biA + eoArr[i];
      const float ciA1 = biA + eoArr[i + 1];
      const float ciB0 = biB + eoArr[i];
      const float ciB1 = biB + eoArr[i + 1];
      const float pA0 = EXP2(dot8i(qA0, kbuf[i],     ciA0));
      const float pA1 = EXP2(dot8i(qA1, kbuf[i + 1], ciA1));
      const float pB0 = EXP2(dot8i(qB0, kbuf[i],     ciB0));
      const float pB1 = EXP2(dot8i(qB1, kbuf[i + 1], ciB1));
      lA0 += pA0; lA1 += pA1; lB0 += pB0; lB1 += pB1;
      const half_t hA0 = (half_t)pA0, hA1 = (half_t)pA1;
      const half_t hB0 = (half_t)pB0, hB1 = (half_t)pB1;
      const h2 qA0v = { hA0, hA0 }, qA1v = { hA1, hA1 };
      const h2 qB0v = { hB0, hB0 }, qB1v = { hB1, hB1 };
      const uint4 v0 = vbuf[i], v1 = vbuf[i + 1];
      const h2 w00 = as_h2(v0.x), w01 = as_h2(v0.y), w02 = as_h2(v0.z), w03 = as_h2(v0.w);
      const h2 w10 = as_h2(v1.x), w11 = as_h2(v1.y), w12 = as_h2(v1.z), w13 = as_h2(v1.w);
      aA0[0] += qA0v * w00; aA0[1] += qA0v * w01; aA0[2] += qA0v * w02; aA0[3] += qA0v * w03;
      aA1[0] += qA1v * w10; aA1[1] += qA1v * w11; aA1[2] += qA1v * w12; aA1[3] += qA1v * w13;
      aB0[0] += qB0v * w00; aB0[1] += qB0v * w01; aB0[2] += qB0v * w02; aB0[3] += qB0v * w03;
      aB1[0] += qB1v * w10; aB1[1] += qB1v * w11; aB1[2] += qB1v * w12; aB1[3] += qB1v * w13;
    }
  }

  // ---- store frame-partials: pa/pl [s][h][btpix], each written once ----
  const size_t plane = (size_t)(s * NH + h) * NPIX + (size_t)(b * NT + t) * HW;
  union { h2 hh[4]; uint4 u; } c0, c1, c2, c3;
  #pragma unroll
  for (int i = 0; i < 4; ++i) { c0.hh[i] = aA0[i]; c1.hh[i] = aA1[i];
                                c2.hh[i] = aB0[i]; c3.hh[i] = aB1[i]; }
  pa[plane + pixA0] = c0.u;
  pa[plane + pixA1] = c1.u;
  pa[plane + pixB0] = c2.u;
  pa[plane + pixB1] = c3.u;
  pl[plane + pixA0] = lA0;
  pl[plane + pixA1] = lA1;
  pl[plane + pixB0] = lB0;
  pl[plane + pixB1] = lB1;
}

__global__ __launch_bounds__(128) void attn_kernel(
    const uint4* __restrict__ qf, const uint4* __restrict__ kf,
    const uint4* __restrict__ vf, uint4* __restrict__ pa, float* __restrict__ pl)
{
  __shared__ uint4 k_lds[16 * LSTRIDE];   // 16.25 KB (padded rows)
  __shared__ uint4 v_lds[16 * LSTRIDE];   // 16.25 KB
  const int bid = blockIdx.x;        // 1600 = 10(bt) * 5(s) * 8(yb) * 4(h)
  // Longest-job-first: bids 0..799 -> R4 heads {2,3}; 800..1599 -> R3 {0,1}.
  int h, rest;
  if (bid < 800) { h = 2 + (bid & 1); rest = bid >> 1; }
  else           { h = ((bid - 800) & 1); rest = (bid - 800) >> 1; }
  const int yb = rest & 7; rest >>= 3;
  const int s  = rest % 5;
  const int bt = rest / 5;
  const int t = bt % NT, b = bt / NT;
  if      (h == 0) attn_body<3, 1>(b, t, 0, s, yb, qf, kf, vf, pa, pl, k_lds, v_lds);
  else if (h == 1) attn_body<3, 2>(b, t, 1, s, yb, qf, kf, vf, pa, pl, k_lds, v_lds);
  else if (h == 2) attn_body<4, 1>(b, t, 2, s, yb, qf, kf, vf, pa, pl, k_lds, v_lds);
  else             attn_body<4, 2>(b, t, 3, s, yb, qf, kf, vf, pa, pl, k_lds, v_lds);
}

// ---------------- Kernel C1: plane reduce + normalize -> of (fp16) ----------
// R24 proven: reads the 20 planes ONCE (20 MB), normalizes, writes 2.6 MB.
// dim3(160,4) -> 640 blocks, 10 waves/CU.
__global__ __launch_bounds__(256) void reduce_kernel(
    const uint4* __restrict__ pa, const float* __restrict__ pl,
    uint4* __restrict__ of)
{
  const int p = blockIdx.x * 256 + threadIdx.x;     // btpix 0..40959
  const int h = blockIdx.y;                         // head 0..3

  float a[8], l = 0.f;
  #pragma unroll
  for (int i = 0; i < 8; ++i) a[i] = 0.f;
  #pragma unroll
  for (int s = 0; s < NT; ++s) {
    const size_t plane = (size_t)(s * NH + h) * NPIX + p;
    const uint4 v = pa[plane];
    l += pl[plane];
    const h2 v0 = as_h2(v.x), v1 = as_h2(v.y), v2 = as_h2(v.z), v3 = as_h2(v.w);
    a[0] += (float)v0.x; a[1] += (float)v0.y;
    a[2] += (float)v1.x; a[3] += (float)v1.y;
    a[4] += (float)v2.x; a[5] += (float)v2.y;
    a[6] += (float)v3.x; a[7] += (float)v3.y;
  }
  const float inv = 1.0f / l;
  uint4 r;
  r.x = pack_h2(a[0] * inv, a[1] * inv);
  r.y = pack_h2(a[2] * inv, a[3] * inv);
  r.z = pack_h2(a[4] * inv, a[5] * inv);
  r.w = pack_h2(a[6] * inv, a[7] * inv);
  of[(size_t)h * NPIX + p] = r;
}

// ---------------- Kernel C2: Wo projection + residual (R24 proven) ----------
// of holds final normalized per-head fp16x8 (2.6 MB, L2-resident).
// dim3(160,8) -> 1280 blocks, 20 waves/CU.
__global__ __launch_bounds__(256) void proj_kernel(
    const uint4* __restrict__ of, const float* __restrict__ x,
    const float* __restrict__ Wo, float* __restrict__ out)
{
  const int p   = blockIdx.x * 256 + threadIdx.x;   // btpix 0..40959
  const int og  = blockIdx.y;                       // 4 out-channels per og
  const int bt  = p >> 12;
  const int pix = p & 4095;

  float oc[32];
  #pragma unroll
  for (int h = 0; h < NH; ++h) {
    const uint4 v = of[(size_t)h * NPIX + p];
    const h2 v0 = as_h2(v.x), v1 = as_h2(v.y), v2 = as_h2(v.z), v3 = as_h2(v.w);
    oc[h * 8 + 0] = (float)v0.x; oc[h * 8 + 1] = (float)v0.y;
    oc[h * 8 + 2] = (float)v1.x; oc[h * 8 + 3] = (float)v1.y;
    oc[h * 8 + 4] = (float)v2.x; oc[h * 8 + 5] = (float)v2.y;
    oc[h * 8 + 6] = (float)v3.x; oc[h * 8 + 7] = (float)v3.y;
  }

  const float* xpt = x + (size_t)bt * (NC * HW) + pix;
  float* yp = out + (size_t)bt * (NC * HW) + pix;
  #pragma unroll
  for (int oo = 0; oo < 4; ++oo) {
    const int o = og * 4 + oo;
    float acc = xpt[(size_t)o * HW];                // residual
    #pragma unroll
    for (int c = 0; c < NC; ++c)
      acc = fmaf(oc[c], Wo[o * NC + c], acc);
    yp[(size_t)o * HW] = acc;
  }
}

extern "C" void kernel_launch(void* const* d_in, const int* in_sizes, int n_in,
                              void* d_out, int out_size, void* d_ws, size_t ws_size,
                              hipStream_t stream)
{
  const float* x  = (const float*)d_in[0];
  const float* Wq = (const float*)d_in[1];
  const float* Wk = (const float*)d_in[2];
  const float* Wv = (const float*)d_in[3];
  const float* Wo = (const float*)d_in[4];

  char* ws = (char*)d_ws;
  uint2* qf = (uint2*)ws;                             //  2,621,440 B
  uint2* kf = (uint2*)(ws + 2621440);                 //  2,621,440 B
  uint2* vf = (uint2*)(ws + 2 * 2621440);             //  2,621,440 B
  uint4* pa = (uint4*)(ws + 3 * 2621440);             // 13,107,200 B (fp16x8 partials)
  float* pl = (float*)(ws + 3 * 2621440 + 13107200);  //  3,276,800 B (fp32 l)
  uint4* of = (uint4*)(ws + 3 * 2621440 + 13107200 + 3276800); // 2,621,440 B

  qkv_kernel<<<dim3(160, 8), 256, 0, stream>>>(x, Wq, Wk, Wv, qf, kf, vf);
  attn_kernel<<<1600, 128, 0, stream>>>((const uint4*)qf, (const uint4*)kf,
                                        (const uint4*)vf, pa, pl);
  reduce_kernel<<<dim3(160, 4), 256, 0, stream>>>((const uint4*)pa, pl, of);
  proj_kernel<<<dim3(160, 8), 256, 0, stream>>>((const uint4*)of, x, Wo,
                                                (float*)d_out);
}

// Round 14
// 110.590 us; speedup vs baseline: 1.0932x; 1.0558x over previous
//
#include <hip/hip_runtime.h>
#include <stdint.h>

#define NT 5
#define NC 32
#define NH 4
#define HW 4096             // 64*64
#define NPIX 40960          // (b*t)*HW
#define QS 0.51006972789f   // (1/sqrt(8)) * log2(e): fold scale + ln->log2 into q
#define EBIAS 12.0f         // softmax shift: p = 2^(e-EBIAS); cancels in acc/l
#define NINF (-__builtin_inff())

typedef _Float16 half_t;
typedef half_t h2 __attribute__((ext_vector_type(2)));

static __device__ __forceinline__ h2 as_h2(uint32_t u) {
  union { uint32_t u; h2 h; } c; c.u = u; return c.h;
}
static __device__ __forceinline__ uint32_t pack_h2(float a, float b) {
  union { h2 h; uint32_t u; } c;
  c.h.x = (half_t)a; c.h.y = (half_t)b;
  return c.u;
}

#if __has_builtin(__builtin_amdgcn_exp2f)
#define EXP2(x) __builtin_amdgcn_exp2f(x)
#else
#define EXP2(x) exp2f(x)
#endif

// dot8 with runtime init accumulator (carries -EBIAS and the 0/-inf masks free)
static __device__ __forceinline__ float dot8i(const uint4& a, const uint4& b, float c) {
#if __has_builtin(__builtin_amdgcn_fdot2)
  c = __builtin_amdgcn_fdot2(as_h2(a.x), as_h2(b.x), c, false);
  c = __builtin_amdgcn_fdot2(as_h2(a.y), as_h2(b.y), c, false);
  c = __builtin_amdgcn_fdot2(as_h2(a.z), as_h2(b.z), c, false);
  c = __builtin_amdgcn_fdot2(as_h2(a.w), as_h2(b.w), c, false);
  return c;
#else
  const h2 a0 = as_h2(a.x), a1 = as_h2(a.y), a2 = as_h2(a.z), a3 = as_h2(a.w);
  const h2 b0 = as_h2(b.x), b1 = as_h2(b.y), b2 = as_h2(b.z), b3 = as_h2(b.w);
  c = fmaf((float)a0.x, (float)b0.x, c);
  c = fmaf((float)a0.y, (float)b0.y, c);
  c = fmaf((float)a1.x, (float)b1.x, c);
  c = fmaf((float)a1.y, (float)b1.y, c);
  c = fmaf((float)a2.x, (float)b2.x, c);
  c = fmaf((float)a2.y, (float)b2.y, c);
  c = fmaf((float)a3.x, (float)b3.x, c);
  c = fmaf((float)a3.y, (float)b3.y, c);
  return c;
#endif
}

// ---------------- Kernel A: QKV projection (R13 proven: ~11 us) -------------
// Split per (head x output-quad): dim3(160,8) -> 1280 blocks, 20 waves/CU.
__global__ __launch_bounds__(256) void qkv_kernel(
    const float* __restrict__ x,
    const float* __restrict__ Wq, const float* __restrict__ Wk,
    const float* __restrict__ Wv,
    uint2* __restrict__ qf, uint2* __restrict__ kf, uint2* __restrict__ vf)
{
  const int p   = blockIdx.x * 256 + threadIdx.x;   // 0..40959
  const int by  = blockIdx.y;                       // 0..7
  const int h   = by >> 1;
  const int jg  = by & 1;
  const int bt  = p >> 12;
  const int pix = p & 4095;

  const float* xp = x + (size_t)bt * (NC * HW) + pix;
  float xc[NC];
  #pragma unroll
  for (int c = 0; c < NC; ++c) xc[c] = xp[(size_t)c * HW];

  float qv[4], kv4[4], vv4[4];
  #pragma unroll
  for (int j = 0; j < 4; ++j) {
    const int o = h * 8 + jg * 4 + j;
    float aq = 0.f, ak = 0.f, av = 0.f;
    #pragma unroll
    for (int c = 0; c < NC; ++c) {
      const float xv = xc[c];
      aq = fmaf(xv, Wq[o * NC + c], aq);
      ak = fmaf(xv, Wk[o * NC + c], ak);
      av = fmaf(xv, Wv[o * NC + c], av);
    }
    qv[j] = aq * QS; kv4[j] = ak; vv4[j] = av;
  }
  const size_t base = (((size_t)bt * NH + h) * HW + pix) * 2 + jg;
  uint2 qq, kk, vv;
  qq.x = pack_h2(qv[0], qv[1]);  qq.y = pack_h2(qv[2], qv[3]);
  kk.x = pack_h2(kv4[0], kv4[1]); kk.y = pack_h2(kv4[2], kv4[3]);
  vv.x = pack_h2(vv4[0], vv4[1]); vv.y = pack_h2(vv4[2], vv4[3]);
  qf[base] = qq;
  kf[base] = kk;
  vf[base] = vv;
}

// ---------------- Kernel B: neighborhood attention (R21, best known) --------
// 256-thr pair body, K+V LDS, 2-deep dx register pipeline, dx-invariant
// hoisting (posArr/eoArr), LJF dispatch. 1600 blocks, 32 KB LDS.
template <int R, int D>
static __device__ __forceinline__ void attn_body(
    int b, int t, int h, int s, int yb,
    const uint4* __restrict__ qf, const uint4* __restrict__ kf,
    const uint4* __restrict__ vf,
    uint4* __restrict__ pa, float* __restrict__ pl,
    uint4* __restrict__ k_lds, uint4* __restrict__ v_lds)
{
  constexpr int LS    = 2 * R + 1;
  constexpr int NROWS = 8 + 2 * R;        // staged key rows (step D): 14 or 16
  const int tid  = threadIdx.x;
  const int w    = tid >> 6;              // wave 0..3
  const int lane = tid & 63;

  // first query row of this block (D2: yb&1 = row parity, 8 same-parity rows)
  const int y0 = (D == 1) ? (yb * 8) : ((yb & 1) + 2 * ((yb >> 1) * 8));

  // ---- stage NROWS full-width K,V rows into LDS (coalesced) ----
  const uint4* kg = kf + (size_t)((b * NT + s) * NH + h) * HW;
  const uint4* vg = vf + (size_t)((b * NT + s) * NH + h) * HW;
  for (int idx = tid; idx < NROWS * 64; idx += 256) {
    const int r  = idx >> 6, xs = idx & 63;
    int ys = y0 + (r - R) * D;
    ys = ys < 0 ? 0 : (ys > 63 ? 63 : ys);          // clamp; masked at compute
    const int pos = (D == 1) ? xs : ((xs & 1) * 32 + (xs >> 1));
    k_lds[r * 64 + pos] = kg[ys * 64 + xs];
    v_lds[r * 64 + pos] = vg[ys * 64 + xs];
  }
  __syncthreads();

  const int xp = lane >> 5;                          // D2 x-parity
  const int cb = (D == 1) ? lane : (lane & 31);      // compressed x
  const int x  = (D == 1) ? lane : (2 * (lane & 31) + xp);
  const int yA = y0 + 2 * w * D;
  const int yB = yA + D;
  const int pixA = yA * 64 + x, pixB = yB * 64 + x;

  const uint4* qp = qf + (size_t)((b * NT + t) * NH + h) * HW;
  const uint4 qA = qp[pixA];
  const uint4 qB = qp[pixB];

  // ---- dx-invariant hoisting: LDS position + col mask per dx ----
  int   posArr[LS];
  float eoArr[LS];
  #pragma unroll
  for (int i = 0; i < LS; ++i) {
    const int  cx  = cb + i - R;
    const bool okx = (unsigned)cx < (D == 1 ? 64u : 32u);
    const int  cc  = okx ? cx : 0;
    posArr[i] = (D == 1) ? cc : (xp * 32 + cc);
    eoArr[i]  = okx ? 0.f : NINF;
  }

  float lA = 0.f, lB = 0.f;
  h2 aA[4], aB[4];
  const h2 z2 = { (half_t)0.f, (half_t)0.f };
  #pragma unroll
  for (int i = 0; i < 4; ++i) { aA[i] = z2; aB[i] = z2; }

  #pragma unroll 2
  for (int u = 0; u <= LS; ++u) {                    // key-row sweep, pair-shared
    const int ykey = y0 + (2 * w + u - R) * D;       // key row y (same for A,B)
    const bool oky = (unsigned)ykey < 64u;
    const bool okA = (u < LS) && oky;
    const bool okB = (u > 0)  && oky;
    if (!(okA || okB)) continue;                     // wave-uniform skip
    const float biA = okA ? -EBIAS : NINF;           // row mask folded into dot
    const float biB = okB ? -EBIAS : NINF;
    const uint4* kr = k_lds + (2 * w + u) * 64;
    const uint4* vr = v_lds + (2 * w + u) * 64;

    // ---- 2-deep register pipeline over dx (indices static after unroll) ----
    uint4 kbuf[2], vbuf[2];
    #pragma unroll
    for (int i = 0; i < 2; ++i) {
      kbuf[i] = kr[posArr[i]];
      vbuf[i] = vr[posArr[i]];
    }
    #pragma unroll
    for (int i = 0; i < LS; ++i) {
      const uint4 kk = kbuf[i & 1];
      const uint4 vv = vbuf[i & 1];
      if (i + 2 < LS) {                              // issue dx+2 loads early
        kbuf[i & 1] = kr[posArr[i + 2]];
        vbuf[i & 1] = vr[posArr[i + 2]];
      }
      const float ciA = biA + eoArr[i];              // col+row mask, 1 add
      const float ciB = biB + eoArr[i];
      const float pA = EXP2(dot8i(qA, kk, ciA));
      const float pB = EXP2(dot8i(qB, kk, ciB));
      lA += pA; lB += pB;
      const half_t pAh = (half_t)pA, pBh = (half_t)pB;
      const h2 pA2 = { pAh, pAh }, pB2 = { pBh, pBh };
      const h2 w0 = as_h2(vv.x), w1 = as_h2(vv.y), w2 = as_h2(vv.z), w3 = as_h2(vv.w);
      aA[0] += pA2 * w0; aA[1] += pA2 * w1; aA[2] += pA2 * w2; aA[3] += pA2 * w3;
      aB[0] += pB2 * w0; aB[1] += pB2 * w1; aB[2] += pB2 * w2; aB[3] += pB2 * w3;
    }
  }

  // ---- store frame-partials: pa/pl [s][h][btpix], each written once ----
  const size_t plane = (size_t)(s * NH + h) * NPIX + (size_t)(b * NT + t) * HW;
  union { h2 hh[4]; uint4 u; } cA, cB;
  #pragma unroll
  for (int i = 0; i < 4; ++i) { cA.hh[i] = aA[i]; cB.hh[i] = aB[i]; }
  pa[plane + pixA] = cA.u;
  pa[plane + pixB] = cB.u;
  pl[plane + pixA] = lA;
  pl[plane + pixB] = lB;
}

__global__ __launch_bounds__(256) void attn_kernel(
    const uint4* __restrict__ qf, const uint4* __restrict__ kf,
    const uint4* __restrict__ vf, uint4* __restrict__ pa, float* __restrict__ pl)
{
  __shared__ uint4 k_lds[16 * 64];   // 16 KB
  __shared__ uint4 v_lds[16 * 64];   // 16 KB
  const int bid = blockIdx.x;        // 1600 = 10(bt) * 5(s) * 8(yb) * 4(h)
  // Longest-job-first: bids 0..799 -> R4 heads {2,3}; 800..1599 -> R3 {0,1}.
  int h, rest;
  if (bid < 800) { h = 2 + (bid & 1); rest = bid >> 1; }
  else           { h = ((bid - 800) & 1); rest = (bid - 800) >> 1; }
  const int yb = rest & 7; rest >>= 3;
  const int s  = rest % 5;
  const int bt = rest / 5;
  const int t = bt % NT, b = bt / NT;
  if      (h == 0) attn_body<3, 1>(b, t, 0, s, yb, qf, kf, vf, pa, pl, k_lds, v_lds);
  else if (h == 1) attn_body<3, 2>(b, t, 1, s, yb, qf, kf, vf, pa, pl, k_lds, v_lds);
  else if (h == 2) attn_body<4, 1>(b, t, 2, s, yb, qf, kf, vf, pa, pl, k_lds, v_lds);
  else             attn_body<4, 2>(b, t, 3, s, yb, qf, kf, vf, pa, pl, k_lds, v_lds);
}

// ---------------- Kernel C1: plane reduce + normalize -> of (fp16) ----------
// R24 proven: reads the 20 planes ONCE (20 MB), normalizes, writes 2.6 MB.
// dim3(160,4) -> 640 blocks, 10 waves/CU.
__global__ __launch_bounds__(256) void reduce_kernel(
    const uint4* __restrict__ pa, const float* __restrict__ pl,
    uint4* __restrict__ of)
{
  const int p = blockIdx.x * 256 + threadIdx.x;     // btpix 0..40959
  const int h = blockIdx.y;                         // head 0..3

  float a[8], l = 0.f;
  #pragma unroll
  for (int i = 0; i < 8; ++i) a[i] = 0.f;
  #pragma unroll
  for (int s = 0; s < NT; ++s) {
    const size_t plane = (size_t)(s * NH + h) * NPIX + p;
    const uint4 v = pa[plane];
    l += pl[plane];
    const h2 v0 = as_h2(v.x), v1 = as_h2(v.y), v2 = as_h2(v.z), v3 = as_h2(v.w);
    a[0] += (float)v0.x; a[1] += (float)v0.y;
    a[2] += (float)v1.x; a[3] += (float)v1.y;
    a[4] += (float)v2.x; a[5] += (float)v2.y;
    a[6] += (float)v3.x; a[7] += (float)v3.y;
  }
  const float inv = 1.0f / l;
  uint4 r;
  r.x = pack_h2(a[0] * inv, a[1] * inv);
  r.y = pack_h2(a[2] * inv, a[3] * inv);
  r.z = pack_h2(a[4] * inv, a[5] * inv);
  r.w = pack_h2(a[6] * inv, a[7] * inv);
  of[(size_t)h * NPIX + p] = r;
}

// ---------------- Kernel C2: Wo projection + residual (R24 proven) ----------
// of holds final normalized per-head fp16x8 (2.6 MB, L2-resident).
// dim3(160,8) -> 1280 blocks, 20 waves/CU.
__global__ __launch_bounds__(256) void proj_kernel(
    const uint4* __restrict__ of, const float* __restrict__ x,
    const float* __restrict__ Wo, float* __restrict__ out)
{
  const int p   = blockIdx.x * 256 + threadIdx.x;   // btpix 0..40959
  const int og  = blockIdx.y;                       // 4 out-channels per og
  const int bt  = p >> 12;
  const int pix = p & 4095;

  float oc[32];
  #pragma unroll
  for (int h = 0; h < NH; ++h) {
    const uint4 v = of[(size_t)h * NPIX + p];
    const h2 v0 = as_h2(v.x), v1 = as_h2(v.y), v2 = as_h2(v.z), v3 = as_h2(v.w);
    oc[h * 8 + 0] = (float)v0.x; oc[h * 8 + 1] = (float)v0.y;
    oc[h * 8 + 2] = (float)v1.x; oc[h * 8 + 3] = (float)v1.y;
    oc[h * 8 + 4] = (float)v2.x; oc[h * 8 + 5] = (float)v2.y;
    oc[h * 8 + 6] = (float)v3.x; oc[h * 8 + 7] = (float)v3.y;
  }

  const float* xpt = x + (size_t)bt * (NC * HW) + pix;
  float* yp = out + (size_t)bt * (NC * HW) + pix;
  #pragma unroll
  for (int oo = 0; oo < 4; ++oo) {
    const int o = og * 4 + oo;
    float acc = xpt[(size_t)o * HW];                // residual
    #pragma unroll
    for (int c = 0; c < NC; ++c)
      acc = fmaf(oc[c], Wo[o * NC + c], acc);
    yp[(size_t)o * HW] = acc;
  }
}

extern "C" void kernel_launch(void* const* d_in, const int* in_sizes, int n_in,
                              void* d_out, int out_size, void* d_ws, size_t ws_size,
                              hipStream_t stream)
{
  const float* x  = (const float*)d_in[0];
  const float* Wq = (const float*)d_in[1];
  const float* Wk = (const float*)d_in[2];
  const float* Wv = (const float*)d_in[3];
  const float* Wo = (const float*)d_in[4];

  char* ws = (char*)d_ws;
  uint2* qf = (uint2*)ws;                             //  2,621,440 B
  uint2* kf = (uint2*)(ws + 2621440);                 //  2,621,440 B
  uint2* vf = (uint2*)(ws + 2 * 2621440);             //  2,621,440 B
  uint4* pa = (uint4*)(ws + 3 * 2621440);             // 13,107,200 B (fp16x8 partials)
  float* pl = (float*)(ws + 3 * 2621440 + 13107200);  //  3,276,800 B (fp32 l)
  uint4* of = (uint4*)(ws + 3 * 2621440 + 13107200 + 3276800); // 2,621,440 B

  qkv_kernel<<<dim3(160, 8), 256, 0, stream>>>(x, Wq, Wk, Wv, qf, kf, vf);
  attn_kernel<<<1600, 256, 0, stream>>>((const uint4*)qf, (const uint4*)kf,
                                        (const uint4*)vf, pa, pl);
  reduce_kernel<<<dim3(160, 4), 256, 0, stream>>>((const uint4*)pa, pl, of);
  proj_kernel<<<dim3(160, 8), 256, 0, stream>>>((const uint4*)of, x, Wo,
                                                (float*)d_out);
}